// Round 11
// baseline (38.746 us; speedup 1.0000x reference)
//
#include <hip/hip_runtime.h>
#include <math.h>

static constexpr int B_ = 32;
static constexpr int T_ = 512;
static constexpr int D_ = 1024;
static constexpr int WROWS_ = 64;                // rows per unit
static constexpr int SLICE4_ = 32;               // float4 per D-slice (128 floats)
static constexpr int NSL_ = (D_ / 4) / SLICE4_;  // 8 slices
static constexpr int GRID1_ = 1024;              // 4 blocks/CU
static constexpr float EPS_ = 1e-12f;

__device__ __forceinline__ float sl1f(float x) {
    float a = fabsf(x);
    return a < 1.0f ? 0.5f * x * x : a - 0.5f;
}

__device__ __forceinline__ float blockReduce256(float v, float* lds) {
#pragma unroll
    for (int o = 32; o > 0; o >>= 1) v += __shfl_down(v, o, 64);
    int wid = threadIdx.x >> 6, lane = threadIdx.x & 63;
    if (lane == 0) lds[wid] = v;
    __syncthreads();
    float tot = lds[0] + lds[1] + lds[2] + lds[3];
    __syncthreads();
    return tot;
}

// LLC-coherent (sc0 sc1) data path: relaxed system-scope atomics compile to
// plain global_store/load with coherence bits set — write-through to LLC,
// NO wbl2/inv (R3's killer), NO RMW (R8's killer).
__device__ __forceinline__ void store_f4_sc(float4* dst, float4 v) {
    unsigned long long* p = reinterpret_cast<unsigned long long*>(dst);
    union { float2 f; unsigned long long u; } lo, hi;
    lo.f = make_float2(v.x, v.y); hi.f = make_float2(v.z, v.w);
    __hip_atomic_store(p, lo.u, __ATOMIC_RELAXED, __HIP_MEMORY_SCOPE_SYSTEM);
    __hip_atomic_store(p + 1, hi.u, __ATOMIC_RELAXED, __HIP_MEMORY_SCOPE_SYSTEM);
}
__device__ __forceinline__ float4 load_f4_sc(const float4* src) {
    const unsigned long long* p = reinterpret_cast<const unsigned long long*>(src);
    unsigned long long a = __hip_atomic_load(p, __ATOMIC_RELAXED, __HIP_MEMORY_SCOPE_SYSTEM);
    unsigned long long b = __hip_atomic_load(p + 1, __ATOMIC_RELAXED, __HIP_MEMORY_SCOPE_SYSTEM);
    union { unsigned long long u; float2 f; } ua, ub;
    ua.u = a; ub.u = b;
    return make_float4(ua.f.x, ua.f.y, ub.f.x, ub.f.y);
}

// Init: zero the B_+1 chain counters (1-block node; safe vs first-call garbage).
__global__ __launch_bounds__(64) void init_kernel(int* __restrict__ ctrs) {
    if (threadIdx.x < B_ + 1) ctrs[threadIdx.x] = 0;
}

// Main: flat-balanced unit loop (R10 structure) + inline per-sample finish.
// Unit = (b, slice s, window w). Producer protocol per unit (all in wave 0):
// sc1-store partials -> s_waitcnt vmcnt(0) -> relaxed atomicAdd(ctr[b]).
// The add that completes sample b's unit count runs b's finish on this block
// (sc1 loads — reads straight from LLC, no cache maintenance). The 32nd
// finisher sums wsPerB and plain-stores out[0] (end-of-kernel flush publishes).
// Deterministic: fixed combine order, single writer for out[0].
__global__ __launch_bounds__(256, 4) void main_kernel(
    const float* __restrict__ preds, const float* __restrict__ wtarg,
    const float* __restrict__ img, const int* __restrict__ lens,
    float* __restrict__ wsPred, float* __restrict__ wsTarg,
    float* __restrict__ wsSl1, float* __restrict__ wsPerB,
    int* __restrict__ ctrs, float* __restrict__ out)
{
    __shared__ float4 redP[8][SLICE4_];
    __shared__ float4 redT[8][SLICE4_];
    __shared__ float lred[4];
    __shared__ int sEx[B_ + 1];
    __shared__ int sNwin[B_];
    __shared__ int sLen[B_];
    __shared__ int sFinB;
    __shared__ int sFin2;

    const int tid = threadIdx.x;

    if (tid < 64) {
        int len_t = (tid < B_) ? lens[tid] : 0;
        int nwin = (len_t + WROWS_ - 1) / WROWS_;
        int nu = nwin * NSL_;
        int incl = nu;
#pragma unroll
        for (int o = 1; o < 64; o <<= 1) {
            int u = __shfl_up(incl, o, 64);
            if (tid >= o) incl += u;
        }
        if (tid < B_) { sEx[tid] = incl - nu; sNwin[tid] = nwin; sLen[tid] = len_t; }
        if (tid == B_ - 1) sEx[B_] = incl;
    }
    __syncthreads();
    const int total = sEx[B_];

    const int j = tid & (SLICE4_ - 1);
    const int r8 = tid >> 5;
    const float4* img4 = reinterpret_cast<const float4*>(img);

    for (int fu = blockIdx.x; fu < total; fu += GRID1_) {
        // decode unit (uniform across block)
        int lo = 0, hi = B_;
        while (hi - lo > 1) {
            int mid = (lo + hi) >> 1;
            if (sEx[mid] <= fu) lo = mid; else hi = mid;
        }
        const int b = lo;
        const int rem = fu - sEx[b];
        const int nwin = sNwin[b];
        const int s = rem / nwin;
        const int w = rem - s * nwin;
        const int len = sLen[b];
        const int t0 = w * WROWS_;
        const int nr = min(WROWS_, len - t0);

        const float4* pp = reinterpret_cast<const float4*>(preds)
                           + (size_t)(b * T_ + t0) * (D_ / 4) + s * SLICE4_ + j;
        const float4* pw = reinterpret_cast<const float4*>(wtarg)
                           + (size_t)(b * T_ + t0) * (D_ / 4) + s * SLICE4_ + j;

        float4 ps = make_float4(0.f, 0.f, 0.f, 0.f);
        float4 ts = make_float4(0.f, 0.f, 0.f, 0.f);
        float sl = 0.f;

        if (nr == WROWS_) {
            float4 p[8], wv[8];
#pragma unroll
            for (int k = 0; k < 8; ++k) p[k] = pp[(size_t)(r8 + 8 * k) * (D_ / 4)];
#pragma unroll
            for (int k = 0; k < 8; ++k) wv[k] = pw[(size_t)(r8 + 8 * k) * (D_ / 4)];
#pragma unroll
            for (int k = 0; k < 8; ++k) {
                ps.x += p[k].x; ps.y += p[k].y; ps.z += p[k].z; ps.w += p[k].w;
                ts.x += wv[k].x; ts.y += wv[k].y; ts.z += wv[k].z; ts.w += wv[k].w;
                sl += sl1f(p[k].x - wv[k].x) + sl1f(p[k].y - wv[k].y)
                    + sl1f(p[k].z - wv[k].z) + sl1f(p[k].w - wv[k].w);
            }
        } else {
            for (int k = 0; k < 8; ++k) {
                int r = r8 + 8 * k;
                if (r < nr) {
                    float4 p = pp[(size_t)r * (D_ / 4)];
                    float4 wv = pw[(size_t)r * (D_ / 4)];
                    ps.x += p.x; ps.y += p.y; ps.z += p.z; ps.w += p.w;
                    ts.x += wv.x; ts.y += wv.y; ts.z += wv.z; ts.w += wv.w;
                    sl += sl1f(p.x - wv.x) + sl1f(p.y - wv.y)
                        + sl1f(p.z - wv.z) + sl1f(p.w - wv.w);
                }
            }
        }

        redP[r8][j] = ps;
        redT[r8][j] = ts;
        float tot = blockReduce256(sl, lred);   // syncthreads inside publishes redP/redT

        if (tid < SLICE4_) {
            float4 ap = make_float4(0.f, 0.f, 0.f, 0.f);
            float4 at = make_float4(0.f, 0.f, 0.f, 0.f);
#pragma unroll
            for (int k = 0; k < 8; ++k) {
                float4 a = redP[k][tid], bb = redT[k][tid];
                ap.x += a.x; ap.y += a.y; ap.z += a.z; ap.w += a.w;
                at.x += bb.x; at.y += bb.y; at.z += bb.z; at.w += bb.w;
            }
            const size_t off = (size_t)fu * SLICE4_ + tid;
            store_f4_sc(reinterpret_cast<float4*>(wsPred) + off, ap);
            store_f4_sc(reinterpret_cast<float4*>(wsTarg) + off, at);
        }
        if (tid == 0) {
            __hip_atomic_store(&wsSl1[fu], tot, __ATOMIC_RELAXED, __HIP_MEMORY_SCOPE_SYSTEM);
            asm volatile("s_waitcnt vmcnt(0)" ::: "memory");  // wave-0 stores -> LLC
            int old = atomicAdd(&ctrs[b], 1);                 // relaxed device RMW
            sFinB = (old == nwin * NSL_ - 1) ? b : -1;
        }
        __syncthreads();
        const int fb = sFinB;

        if (fb >= 0) {
            // ---- inline finish for sample fb (all partials LLC-visible) ----
            const int fnwin = sNwin[fb];
            const int fbase = sEx[fb];
            const float flen = (float)sLen[fb];
            const int fs = tid >> 5, fcol = tid & 31;

            float4 aps = make_float4(0.f, 0.f, 0.f, 0.f);
            float4 ats = make_float4(0.f, 0.f, 0.f, 0.f);
            for (int ww = 0; ww < fnwin; ++ww) {
                const size_t off = (size_t)(fbase + fs * fnwin + ww) * SLICE4_ + fcol;
                float4 p = load_f4_sc(reinterpret_cast<const float4*>(wsPred) + off);
                float4 t = load_f4_sc(reinterpret_cast<const float4*>(wsTarg) + off);
                aps.x += p.x; aps.y += p.y; aps.z += p.z; aps.w += p.w;
                ats.x += t.x; ats.y += t.y; ats.z += t.z; ats.w += t.w;
            }

            float4 im = img4[(size_t)fb * (D_ / 4) + tid];   // input: plain load ok
            float ss = im.x * im.x + im.y * im.y + im.z * im.z + im.w * im.w;
            float sumsq = blockReduce256(ss, lred);
            float inv_norm = 1.0f / fmaxf(sqrtf(sumsq), EPS_);

            const float pmx = aps.x / flen, pmy = aps.y / flen, pmz = aps.z / flen, pmw = aps.w / flen;
            const float tmx = ats.x / flen, tmy = ats.y / flen, tmz = ats.z / flen, tmw = ats.w / flen;

            float sv = sl1f(pmx - tmx) + sl1f(pmy - tmy) + sl1f(pmz - tmz) + sl1f(pmw - tmw)
                     + sl1f(pmx - im.x * inv_norm) + sl1f(pmy - im.y * inv_norm)
                     + sl1f(pmz - im.z * inv_norm) + sl1f(pmw - im.w * inv_norm);
            float stot = blockReduce256(sv, lred);

            float wv = 0.f;
            if (tid < fnwin * NSL_)
                wv = __hip_atomic_load(&wsSl1[fbase + tid], __ATOMIC_RELAXED,
                                       __HIP_MEMORY_SCOPE_SYSTEM);
            if (tid < 64) {
#pragma unroll
                for (int o = 32; o > 0; o >>= 1) wv += __shfl_down(wv, o, 64);
            }

            if (tid == 0) {
                float per_b = stot / (float)D_ + wv / (flen * (float)D_);
                __hip_atomic_store(&wsPerB[fb], per_b, __ATOMIC_RELAXED,
                                   __HIP_MEMORY_SCOPE_SYSTEM);
                asm volatile("s_waitcnt vmcnt(0)" ::: "memory");
                int old2 = atomicAdd(&ctrs[B_], 1);
                sFin2 = (old2 == B_ - 1) ? 1 : 0;
            }
            __syncthreads();

            if (sFin2) {
                float v = 0.f;
                if (tid < B_)
                    v = __hip_atomic_load(&wsPerB[tid], __ATOMIC_RELAXED,
                                          __HIP_MEMORY_SCOPE_SYSTEM);
                if (tid < 64) {
#pragma unroll
                    for (int o = 32; o > 0; o >>= 1) v += __shfl_down(v, o, 64);
                }
                if (tid == 0) out[0] = v / (float)B_;   // single writer, plain store
            }
        }
        __syncthreads();   // protect redP/redT + flags before next iteration
    }
}

extern "C" void kernel_launch(void* const* d_in, const int* in_sizes, int n_in,
                              void* d_out, int out_size, void* d_ws, size_t ws_size,
                              hipStream_t stream) {
    const float* wtarg = (const float*)d_in[0];   // word_targets [B,T,D]
    const float* img   = (const float*)d_in[1];   // image_targets [B,D]
    const float* preds = (const float*)d_in[2];   // preds [B,T,D]
    const int*   lens  = (const int*)d_in[3];     // decode_lengths [B]
    float* out = (float*)d_out;

    // max units = B * ceil(T/64) * 8 = 2048
    float* wsPred = (float*)d_ws;                          // 2048*128 floats (1 MB)
    float* wsTarg = wsPred + (size_t)2048 * 128;           // 1 MB
    float* wsSl1  = wsTarg + (size_t)2048 * 128;           // 2048 floats
    float* wsPerB = wsSl1 + 2048;                          // 32 floats
    int*   ctrs   = (int*)(wsPerB + B_);                   // B_+1 ints

    init_kernel<<<1, 64, 0, stream>>>(ctrs);
    main_kernel<<<GRID1_, 256, 0, stream>>>(preds, wtarg, img, lens,
                                            wsPred, wsTarg, wsSl1, wsPerB, ctrs, out);
}

// Round 12
// 24.384 us; speedup vs baseline: 1.5890x; 1.5890x over previous
//
#include <hip/hip_runtime.h>
#include <math.h>

static constexpr int B_ = 32;
static constexpr int T_ = 512;
static constexpr int D_ = 1024;
static constexpr int NT_ = 32;            // t-chunks per sample
static constexpr int TCHUNK_ = T_ / NT_;  // 16 rows per chunk (compile-time)
static constexpr int GRID1_ = 1024;       // pass-1 blocks (4/CU)
static constexpr float EPS_ = 1e-12f;

__device__ __forceinline__ float sl1f(float x) {
    float a = fabsf(x);
    return a < 1.0f ? 0.5f * x * x : a - 0.5f;
}

// Full 256-thread block reduce; returns total broadcast to all threads.
__device__ __forceinline__ float blockReduce256(float v, float* lds) {
#pragma unroll
    for (int o = 32; o > 0; o >>= 1) v += __shfl_down(v, o, 64);
    int wid = threadIdx.x >> 6, lane = threadIdx.x & 63;
    if (lane == 0) lds[wid] = v;
    __syncthreads();
    float tot = lds[0] + lds[1] + lds[2] + lds[3];
    __syncthreads();
    return tot;
}

// Pass 1: flat balanced chunk list (R5 structure; 13.2 us measured via R6 probe,
// 87% of achievable BW for this mixed R/W pattern). Zeroes out[0] each call.
__global__ __launch_bounds__(256, 4) void pass1_kernel(
    const float* __restrict__ preds, const float* __restrict__ wtarg,
    const int* __restrict__ lens,
    float* __restrict__ wsPred, float* __restrict__ wsTarg, float* __restrict__ wsSl1,
    float* __restrict__ out)
{
    __shared__ float lds[4];
    __shared__ int sPrefix[B_ + 1];   // exclusive prefix of ceil(len/16); [B_]=total
    __shared__ int sLen[B_];

    const int tid = threadIdx.x;
    if (blockIdx.x == 0 && tid == 0) out[0] = 0.f;

    if (tid < 64) {
        int len_t = (tid < B_) ? lens[tid] : 0;
        int nc = (len_t + TCHUNK_ - 1) / TCHUNK_;
        int incl = nc;
#pragma unroll
        for (int o = 1; o < 64; o <<= 1) {
            int u = __shfl_up(incl, o, 64);
            if (tid >= o) incl += u;
        }
        if (tid < B_) { sPrefix[tid] = incl - nc; sLen[tid] = len_t; }
        if (tid == B_ - 1) sPrefix[B_] = incl;
    }
    __syncthreads();
    const int total = sPrefix[B_];

    for (int fi = blockIdx.x; fi < total; fi += GRID1_) {
        // binary search: largest b with sPrefix[b] <= fi (uniform across block)
        int lo = 0, hi = B_;
        while (hi - lo > 1) {
            int mid = (lo + hi) >> 1;
            if (sPrefix[mid] <= fi) lo = mid; else hi = mid;
        }
        const int b = lo;
        const int c = fi - sPrefix[lo];
        const int len = sLen[b];
        const int t0 = c * TCHUNK_;
        const int nrows = min(TCHUNK_, len - t0);

        const float4* pp = reinterpret_cast<const float4*>(preds)
                           + (size_t)(b * T_ + t0) * (D_ / 4) + tid;
        const float4* pw = reinterpret_cast<const float4*>(wtarg)
                           + (size_t)(b * T_ + t0) * (D_ / 4) + tid;

        float4 ps = make_float4(0.f, 0.f, 0.f, 0.f);
        float4 ts = make_float4(0.f, 0.f, 0.f, 0.f);
        float s = 0.f;

        if (nrows == TCHUNK_) {
#pragma unroll
            for (int tt = 0; tt < TCHUNK_; tt += 8) {
                float4 p[8], w[8];
#pragma unroll
                for (int j = 0; j < 8; ++j) p[j] = pp[(size_t)(tt + j) * (D_ / 4)];
#pragma unroll
                for (int j = 0; j < 8; ++j) w[j] = pw[(size_t)(tt + j) * (D_ / 4)];
#pragma unroll
                for (int j = 0; j < 8; ++j) {
                    ps.x += p[j].x; ps.y += p[j].y; ps.z += p[j].z; ps.w += p[j].w;
                    ts.x += w[j].x; ts.y += w[j].y; ts.z += w[j].z; ts.w += w[j].w;
                    s += sl1f(p[j].x - w[j].x) + sl1f(p[j].y - w[j].y)
                       + sl1f(p[j].z - w[j].z) + sl1f(p[j].w - w[j].w);
                }
            }
        } else {
            for (int t = 0; t < nrows; ++t) {
                float4 p = pp[(size_t)t * (D_ / 4)];
                float4 w = pw[(size_t)t * (D_ / 4)];
                ps.x += p.x; ps.y += p.y; ps.z += p.z; ps.w += p.w;
                ts.x += w.x; ts.y += w.y; ts.z += w.z; ts.w += w.w;
                s += sl1f(p.x - w.x) + sl1f(p.y - w.y) + sl1f(p.z - w.z) + sl1f(p.w - w.w);
            }
        }

        const size_t off = ((size_t)b * NT_ + c) * (D_ / 4) + tid;
        reinterpret_cast<float4*>(wsPred)[off] = ps;
        reinterpret_cast<float4*>(wsTarg)[off] = ts;

        float tot = blockReduce256(s, lds);
        if (tid == 0) wsSl1[b * NT_ + c] = tot;
    }
}

// Pass 2: grid (8, B_). Combine + all three loss terms; per-(g,b) partial loss
// accumulated into out[0] via device-scope atomicAdd (32*8 = 256 adds total —
// fine at this scale; R8 showed 1M-scale element atomics are fatal).
__global__ __launch_bounds__(256) void pass2_kernel(
    const float* __restrict__ img, const int* __restrict__ lens,
    const float* __restrict__ wsPred, const float* __restrict__ wsTarg,
    const float* __restrict__ wsSl1, float* __restrict__ out)
{
    __shared__ float4 lA[8][32];
    __shared__ float4 lB[8][32];
    __shared__ float lred[4];

    const int g = blockIdx.x, b = blockIdx.y;
    const int tid = threadIdx.x;
    const int c8 = tid >> 5, j = tid & 31;
    const int len = lens[b];
    const float flen = (float)len;
    const int ntmax = (len + TCHUNK_ - 1) / TCHUNK_;   // chunks actually written

    // image norm over the full row (all 256 threads)
    const float4* img4 = reinterpret_cast<const float4*>(img);
    float4 im = img4[(size_t)b * (D_ / 4) + tid];
    float ss = im.x * im.x + im.y * im.y + im.z * im.z + im.w * im.w;
    float sumsq = blockReduce256(ss, lred);
    float inv_norm = 1.0f / fmaxf(sqrtf(sumsq), EPS_);

    // partial chunk reduction (skip never-written chunks: ws is poisoned)
    float4 ap = make_float4(0.f, 0.f, 0.f, 0.f);
    float4 at = make_float4(0.f, 0.f, 0.f, 0.f);
#pragma unroll
    for (int k = 0; k < NT_ / 8; ++k) {
        int nt = c8 + k * 8;
        if (nt < ntmax) {
            size_t off = ((size_t)b * NT_ + nt) * (D_ / 4) + (size_t)g * 32 + j;
            float4 p = reinterpret_cast<const float4*>(wsPred)[off];
            float4 w = reinterpret_cast<const float4*>(wsTarg)[off];
            ap.x += p.x; ap.y += p.y; ap.z += p.z; ap.w += p.w;
            at.x += w.x; at.y += w.y; at.z += w.z; at.w += w.w;
        }
    }
    lA[c8][j] = ap;
    lB[c8][j] = at;
    __syncthreads();

    float part = 0.f;
    if (tid < 32) {
        float4 ps = make_float4(0.f, 0.f, 0.f, 0.f);
        float4 ts = make_float4(0.f, 0.f, 0.f, 0.f);
#pragma unroll
        for (int k = 0; k < 8; ++k) {
            float4 p = lA[k][tid], w = lB[k][tid];
            ps.x += p.x; ps.y += p.y; ps.z += p.z; ps.w += p.w;
            ts.x += w.x; ts.y += w.y; ts.z += w.z; ts.w += w.w;
        }
        const float pmx = ps.x / flen, pmy = ps.y / flen, pmz = ps.z / flen, pmw = ps.w / flen;
        const float tmx = ts.x / flen, tmy = ts.y / flen, tmz = ts.z / flen, tmw = ts.w / flen;
        float4 iv = img4[(size_t)b * (D_ / 4) + g * 32 + tid];
        part  = sl1f(pmx - tmx) + sl1f(pmy - tmy) + sl1f(pmz - tmz) + sl1f(pmw - tmw);
        part += sl1f(pmx - iv.x * inv_norm) + sl1f(pmy - iv.y * inv_norm)
              + sl1f(pmz - iv.z * inv_norm) + sl1f(pmw - iv.w * inv_norm);
    }
    // reduce 32 lanes of wave 0 (other lanes/waves carry 0)
#pragma unroll
    for (int o = 16; o > 0; o >>= 1) part += __shfl_down(part, o, 64);

    if (tid == 0) {
        float wsum = 0.f;
#pragma unroll
        for (int k = 0; k < NT_ / 8; ++k) {
            int nt = g * (NT_ / 8) + k;
            if (nt < ntmax) wsum += wsSl1[b * NT_ + nt];
        }
        float val = part / (float)D_ + wsum / (flen * (float)D_);
        atomicAdd(out, val * (1.0f / (float)B_));   // device-scope, cross-XCD safe
    }
}

extern "C" void kernel_launch(void* const* d_in, const int* in_sizes, int n_in,
                              void* d_out, int out_size, void* d_ws, size_t ws_size,
                              hipStream_t stream) {
    const float* wtarg = (const float*)d_in[0];   // word_targets [B,T,D]
    const float* img   = (const float*)d_in[1];   // image_targets [B,D]
    const float* preds = (const float*)d_in[2];   // preds [B,T,D]
    const int*   lens  = (const int*)d_in[3];     // decode_lengths [B]
    float* out = (float*)d_out;

    float* wsPred = (float*)d_ws;                          // B*NT*D floats (4 MB)
    float* wsTarg = wsPred + (size_t)B_ * NT_ * D_;        // 4 MB
    float* wsSl1  = wsTarg + (size_t)B_ * NT_ * D_;        // B*NT

    pass1_kernel<<<GRID1_, 256, 0, stream>>>(preds, wtarg, lens, wsPred, wsTarg, wsSl1, out);
    pass2_kernel<<<dim3(8, B_), 256, 0, stream>>>(img, lens, wsPred, wsTarg, wsSl1, out);
}